// Round 4
// baseline (1563.911 us; speedup 1.0000x reference)
//
#include <hip/hip_runtime.h>

#define NN 100000
#define NE 1600000
#define NRG 8      // src ranges (== XCDs); range size 12500
#define RSZ 12500
#define DCH 256    // dst rows per chunk (LDS tile)
#define NCH 391    // chunks: 391*256 = 100096 >= NN
#define NBK (NCH * NRG)  // 3128 buckets, key = (dst>>8)*8 + src/12500
#define EBK 98     // edge blocks of 16384
#define EBSZ 16384
#define NTILES 6250  // NN/16 output tiles

typedef __attribute__((ext_vector_type(8))) short short8;
typedef __attribute__((ext_vector_type(4))) float floatx4;

__device__ __forceinline__ unsigned short f2bf(float f) {
  unsigned u = __float_as_uint(f);
  u += 0x7fffu + ((u >> 16) & 1u);  // RNE
  return (unsigned short)(u >> 16);
}
__device__ __forceinline__ float bf2f(unsigned short b) {
  return __uint_as_float(((unsigned)b) << 16);
}

// ---------------------------------------------------------------------------
// Weights f32 -> bf16 (4 x 64x64).
__global__ __launch_bounds__(256) void k_cvtW(const float* __restrict__ W1,
                                              const float* __restrict__ W2,
                                              const float* __restrict__ W3,
                                              const float* __restrict__ W4,
                                              unsigned short* __restrict__ Wb) {
  int i = blockIdx.x * 256 + threadIdx.x;  // 16*256 = 4096 exact
  Wb[i] = f2bf(W1[i]);
  Wb[4096 + i] = f2bf(W2[i]);
  Wb[8192 + i] = f2bf(W3[i]);
  Wb[12288 + i] = f2bf(W4[i]);
}

// x f32 [NN][64] -> bf16 row-major (agg->bf16 round already dominates error).
__global__ __launch_bounds__(256) void k_cvtX(const float* __restrict__ x,
                                              unsigned short* __restrict__ xb) {
  size_t i = ((size_t)blockIdx.x * 256 + threadIdx.x) * 8;  // 3125 blocks exact
  floatx4 v0 = *(const floatx4*)(x + i);
  floatx4 v1 = *(const floatx4*)(x + i + 4);
  short8 o;
  o[0] = (short)f2bf(v0.x); o[1] = (short)f2bf(v0.y);
  o[2] = (short)f2bf(v0.z); o[3] = (short)f2bf(v0.w);
  o[4] = (short)f2bf(v1.x); o[5] = (short)f2bf(v1.y);
  o[6] = (short)f2bf(v1.z); o[7] = (short)f2bf(v1.w);
  *(short8*)(xb + i) = o;
}

// ---------------------------------------------------------------------------
// Bucket build: key = dstChunk*8 + srcRange. No global atomics.
__global__ __launch_bounds__(256) void k_phist(const int* __restrict__ src,
                                               const int* __restrict__ dst,
                                               int* __restrict__ blockHist) {
  __shared__ int h[NBK];
  for (int i = threadIdx.x; i < NBK; i += 256) h[i] = 0;
  __syncthreads();
  int base = blockIdx.x * EBSZ;
#pragma unroll 4
  for (int i = 0; i < 64; i++) {
    int e = base + i * 256 + threadIdx.x;
    if (e < NE) {
      int key = (dst[e] >> 8) * 8 + src[e] / RSZ;
      atomicAdd(&h[key], 1);
    }
  }
  __syncthreads();
  for (int i = threadIdx.x; i < NBK; i += 256)
    blockHist[(size_t)blockIdx.x * NBK + i] = h[i];
}

// Per-bucket exclusive scan over EBK block counts (in place).
__global__ __launch_bounds__(256) void k_colscan(int* __restrict__ blockHist,
                                                 int* __restrict__ colTot) {
  __shared__ int sh[256];
  int c = blockIdx.x, t = threadIdx.x;
  int v = (t < EBK) ? blockHist[(size_t)t * NBK + c] : 0;
  sh[t] = v;
  __syncthreads();
  for (int off = 1; off < 256; off <<= 1) {
    int u = (t >= off) ? sh[t - off] : 0;
    __syncthreads();
    sh[t] += u;
    __syncthreads();
  }
  if (t < EBK) blockHist[(size_t)t * NBK + c] = sh[t] - v;  // exclusive
  if (t == 255) colTot[c] = sh[255];
}

// Exclusive scan of 3128 bucket totals -> base[0..NBK].
__global__ __launch_bounds__(1024) void k_basescan(const int* __restrict__ colTot,
                                                   int* __restrict__ base) {
  __shared__ int sh[1024];
  int t = threadIdx.x;
  int v[4], s = 0;
#pragma unroll
  for (int i = 0; i < 4; i++) {
    int c = t * 4 + i;
    v[i] = (c < NBK) ? colTot[c] : 0;
    s += v[i];
  }
  sh[t] = s;
  __syncthreads();
  for (int off = 1; off < 1024; off <<= 1) {
    int u = (t >= off) ? sh[t - off] : 0;
    __syncthreads();
    sh[t] += u;
    __syncthreads();
  }
  int ex = sh[t] - s;
#pragma unroll
  for (int i = 0; i < 4; i++) {
    int c = t * 4 + i;
    if (c < NBK) base[c] = ex;
    ex += v[i];
  }
  if (t == 1023) base[NBK] = sh[1023];
}

// Scatter packed edges: ed[pos] = (src<<8) | (dst & 255).
__global__ __launch_bounds__(256) void k_escat(const int* __restrict__ src,
                                               const int* __restrict__ dst,
                                               const int* __restrict__ blockHist,
                                               const int* __restrict__ base,
                                               int* __restrict__ ed) {
  __shared__ int h[NBK];
  for (int i = threadIdx.x; i < NBK; i += 256) h[i] = 0;
  __syncthreads();
  int eb = blockIdx.x * EBSZ;
  const int* ofs = blockHist + (size_t)blockIdx.x * NBK;
#pragma unroll 4
  for (int i = 0; i < 64; i++) {
    int e = eb + i * 256 + threadIdx.x;
    if (e < NE) {
      int d = dst[e], s = src[e];
      int key = (d >> 8) * 8 + s / RSZ;
      int r = atomicAdd(&h[key], 1);
      ed[base[key] + ofs[key] + r] = (s << 8) | (d & 255);
    }
  }
}

// deg[n] = in-degree (needed for the layer-2 affine shift term).
__global__ __launch_bounds__(256) void k_deg(const int* __restrict__ dst,
                                             int* __restrict__ deg) {
  int base = blockIdx.x * 2048;
#pragma unroll
  for (int i = 0; i < 8; i++) {
    int e = base + i * 256 + threadIdx.x;
    if (e < NE) atomicAdd(&deg[dst[e]], 1);
  }
}

// ---------------------------------------------------------------------------
// XCD-pinned push: block = bucket (srcRange k, dstChunk). Runs on XCD k
// (bid&7 == k), whose L2 holds src rows [k*12500, (k+1)*12500) = 1.6 MB bf16.
// Each neighbor row read = ONE 128B L2-hit line (vs 8x16B sliced requests).
// Accumulates into 64KB LDS f32 chunk, flushes f32 partials in MFMA-fragment
// order: slab[k][tile][half(2)][quad(4)][row16][8] (1024 f32 per tile).
__global__ __launch_bounds__(256) void k_push(const unsigned short* __restrict__ X,
                                              const int* __restrict__ ed,
                                              const int* __restrict__ base,
                                              float* __restrict__ slab,
                                              int bucket0, int grptiles) {
  __shared__ float acc[DCH * 64];  // 65536 B
  const int bid = blockIdx.x;
  const int k = bid & 7;
  const int chunkLocal = bid >> 3;
  const int bucket = bucket0 + bid;
  for (int i = threadIdx.x; i < DCH * 64; i += 256) acc[i] = 0.0f;
  __syncthreads();
  const int lo = base[bucket], hi = base[bucket + 1];
  const int l = threadIdx.x & 7;   // feature octet
  const int g = threadIdx.x >> 3;  // edge group 0..31
  for (int e = lo + g; e < hi; e += 64) {  // 2 edges per group per iter
    int u0 = __builtin_nontemporal_load(ed + e);
    int e1 = e + 32;
    bool ok1 = e1 < hi;
    int u1 = ok1 ? __builtin_nontemporal_load(ed + e1) : u0;
    short8 r0 = *(const short8*)(X + (size_t)(u0 >> 8) * 64 + l * 8);
    short8 r1 = *(const short8*)(X + (size_t)(u1 >> 8) * 64 + l * 8);
    int a0 = (u0 & 255) * 64 + l * 8;
#pragma unroll
    for (int j = 0; j < 8; j++) atomicAdd(&acc[a0 + j], bf2f((unsigned short)r0[j]));
    if (ok1) {
      int a1 = (u1 & 255) * 64 + l * 8;
#pragma unroll
      for (int j = 0; j < 8; j++) atomicAdd(&acc[a1 + j], bf2f((unsigned short)r1[j]));
    }
  }
  __syncthreads();
  // flush: thread (row r, octet l) -> fragment layout, nt-stores.
  const size_t kbase = (size_t)k * grptiles;
#pragma unroll
  for (int it = 0; it < 8; it++) {
    int r = it * 32 + g;  // 0..255
    int ab = r * 64 + l * 8;
    floatx4 v0, v1;
    v0[0] = acc[ab]; v0[1] = acc[ab + 1]; v0[2] = acc[ab + 2]; v0[3] = acc[ab + 3];
    v1[0] = acc[ab + 4]; v1[1] = acc[ab + 5]; v1[2] = acc[ab + 6]; v1[3] = acc[ab + 7];
    float* p = slab + (kbase + chunkLocal * 16 + (r >> 4)) * 1024 +
               (l >> 2) * 512 + (l & 3) * 128 + (r & 15) * 8;
    __builtin_nontemporal_store(v0, (floatx4*)p);
    __builtin_nontemporal_store(v1, (floatx4*)(p + 4));
  }
}

// ---------------------------------------------------------------------------
// Fused reduce + MLP: agg = pre(es*self + sum_k slab_k); h2 = relu(relu(agg@Wa
// +ba)@Wb+bb); BN stats to f64. MODE1 applies BN1 affine via linearity:
// agg = A*(es*h + sum) + B*(es + deg).
template <int MODE>
__global__ __launch_bounds__(256) void k_mlp(
    const float* __restrict__ slab, const unsigned short* __restrict__ self,
    const unsigned short* __restrict__ Wab, const float* __restrict__ ba,
    const float* __restrict__ bb, const float* __restrict__ eps,
    const float* __restrict__ AB, const int* __restrict__ deg,
    int rbase, int ntiles, int grptiles,
    unsigned short* __restrict__ hout, double* __restrict__ stats) {
  const int l = threadIdx.x & 63;
  const int wv = threadIdx.x >> 6;
  const int l16 = l & 15, quad = l >> 4;

  short8 wfa[4][2], wfb[4][2];
#pragma unroll
  for (int c = 0; c < 4; c++)
#pragma unroll
    for (int t = 0; t < 2; t++)
#pragma unroll
      for (int j = 0; j < 8; j++) {
        int kk = t * 32 + quad * 8 + j, nn = c * 16 + l16;
        wfa[c][t][j] = (short)Wab[kk * 64 + nn];
        wfb[c][t][j] = (short)Wab[4096 + kk * 64 + nn];
      }
  float bia[4], bib[4];
#pragma unroll
  for (int c = 0; c < 4; c++) { bia[c] = ba[c * 16 + l16]; bib[c] = bb[c * 16 + l16]; }
  const float es = 1.0f + eps[0];
  float A0[8], A1[8], B0[8], B1[8];
  if (MODE) {
#pragma unroll
    for (int j = 0; j < 8; j++) {
      A0[j] = AB[quad * 8 + j];      B0[j] = AB[64 + quad * 8 + j];
      A1[j] = AB[32 + quad * 8 + j]; B1[j] = AB[96 + quad * 8 + j];
    }
  }

  __shared__ float Hs[4][16][68];
  __shared__ float sS[4][64], sQ[4][64];
  float ssum[4] = {0, 0, 0, 0}, ssq[4] = {0, 0, 0, 0};

  for (int tile = blockIdx.x * 4 + wv; tile < ntiles; tile += gridDim.x * 4) {
    const int r0l = tile * 16;
    const int r0 = rbase + r0l;
    short8 sa0 = __builtin_nontemporal_load(
        (const short8*)(self + (size_t)(r0 + l16) * 64 + quad * 8));
    short8 sa1 = __builtin_nontemporal_load(
        (const short8*)(self + (size_t)(r0 + l16) * 64 + 32 + quad * 8));
    float s0[8], s1[8];
#pragma unroll
    for (int j = 0; j < 8; j++) {
      s0[j] = es * bf2f((unsigned short)sa0[j]);
      s1[j] = es * bf2f((unsigned short)sa1[j]);
    }
    const float* sp = slab + (size_t)tile * 1024 + quad * 128 + l16 * 8;
#pragma unroll
    for (int k = 0; k < 8; k++) {
      const float* kp = sp + (size_t)k * grptiles * 1024;
      floatx4 q0 = __builtin_nontemporal_load((const floatx4*)kp);
      floatx4 q1 = __builtin_nontemporal_load((const floatx4*)(kp + 4));
      floatx4 q2 = __builtin_nontemporal_load((const floatx4*)(kp + 512));
      floatx4 q3 = __builtin_nontemporal_load((const floatx4*)(kp + 516));
      s0[0] += q0.x; s0[1] += q0.y; s0[2] += q0.z; s0[3] += q0.w;
      s0[4] += q1.x; s0[5] += q1.y; s0[6] += q1.z; s0[7] += q1.w;
      s1[0] += q2.x; s1[1] += q2.y; s1[2] += q2.z; s1[3] += q2.w;
      s1[4] += q3.x; s1[5] += q3.y; s1[6] += q3.z; s1[7] += q3.w;
    }
    if (MODE) {
      float wd = es + (float)deg[r0 + l16];
#pragma unroll
      for (int j = 0; j < 8; j++) {
        s0[j] = fmaf(s0[j], A0[j], wd * B0[j]);
        s1[j] = fmaf(s1[j], A1[j], wd * B1[j]);
      }
    }
    short8 a0, a1;
#pragma unroll
    for (int j = 0; j < 8; j++) {
      a0[j] = (short)f2bf(s0[j]);
      a1[j] = (short)f2bf(s1[j]);
    }
#pragma unroll
    for (int c = 0; c < 4; c++) {
      floatx4 acc = {0.f, 0.f, 0.f, 0.f};
      acc = __builtin_amdgcn_mfma_f32_16x16x32_bf16(a0, wfa[c][0], acc, 0, 0, 0);
      acc = __builtin_amdgcn_mfma_f32_16x16x32_bf16(a1, wfa[c][1], acc, 0, 0, 0);
#pragma unroll
      for (int r = 0; r < 4; r++)
        Hs[wv][quad * 4 + r][c * 16 + l16] = fmaxf(acc[r] + bia[c], 0.0f);
    }
    short8 a20, a21;
#pragma unroll
    for (int j = 0; j < 8; j++) {
      a20[j] = (short)f2bf(Hs[wv][l16][quad * 8 + j]);
      a21[j] = (short)f2bf(Hs[wv][l16][32 + quad * 8 + j]);
    }
#pragma unroll
    for (int c = 0; c < 4; c++) {
      floatx4 acc = {0.f, 0.f, 0.f, 0.f};
      acc = __builtin_amdgcn_mfma_f32_16x16x32_bf16(a20, wfb[c][0], acc, 0, 0, 0);
      acc = __builtin_amdgcn_mfma_f32_16x16x32_bf16(a21, wfb[c][1], acc, 0, 0, 0);
#pragma unroll
      for (int r = 0; r < 4; r++) {
        float v = fmaxf(acc[r] + bib[c], 0.0f);
        hout[(size_t)(r0 + quad * 4 + r) * 64 + c * 16 + l16] = f2bf(v);
        ssum[c] += v;
        ssq[c] += v * v;
      }
    }
  }
#pragma unroll
  for (int c = 0; c < 4; c++) {
    float s = ssum[c], q = ssq[c];
    s += __shfl_xor(s, 16, 64); s += __shfl_xor(s, 32, 64);
    q += __shfl_xor(q, 16, 64); q += __shfl_xor(q, 32, 64);
    if (quad == 0) { sS[wv][c * 16 + l16] = s; sQ[wv][c * 16 + l16] = q; }
  }
  __syncthreads();
  if (threadIdx.x < 64) {
    int ff = threadIdx.x;
    float s = sS[0][ff] + sS[1][ff] + sS[2][ff] + sS[3][ff];
    float q = sQ[0][ff] + sQ[1][ff] + sQ[2][ff] + sQ[3][ff];
    unsafeAtomicAdd(&stats[ff], (double)s);
    unsafeAtomicAdd(&stats[64 + ff], (double)q);
  }
}

// ---------------------------------------------------------------------------
// stats -> per-feature affine A (scale), B (shift): out = h*A + B
__global__ void k_bnfin(const double* __restrict__ stats, const float* __restrict__ gam,
                        const float* __restrict__ bet, float* __restrict__ AB) {
  int f = threadIdx.x;  // 64 threads
  double mean = stats[f] * (1.0 / NN);
  double var = stats[64 + f] * (1.0 / NN) - mean * mean;
  if (var < 0.0) var = 0.0;
  float rstd = (float)(1.0 / sqrt(var + 1e-5));
  float A = gam[f] * rstd;
  float B = bet[f] - (float)mean * A;
  AB[f] = A;
  AB[64 + f] = B;
}

// ---------------------------------------------------------------------------
// h = BN2(h2); out[0:N*64] = h; out[N*64:] = log_softmax(h). h2 row-major bf16.
__global__ __launch_bounds__(256) void k_out(const unsigned short* __restrict__ h2,
                                             const float* __restrict__ AB,
                                             float* __restrict__ out) {
  int f = threadIdx.x & 63;
  int n = blockIdx.x * 4 + (threadIdx.x >> 6);  // 25000*4 = NN exact
  float v = bf2f(h2[(size_t)n * 64 + f]);
  float h = fmaf(v, AB[f], AB[64 + f]);
  float m = h;
#pragma unroll
  for (int off = 32; off; off >>= 1) m = fmaxf(m, __shfl_xor(m, off, 64));
  float e = expf(h - m);
  float ssum = e;
#pragma unroll
  for (int off = 32; off; off >>= 1) ssum += __shfl_xor(ssum, off, 64);
  float lsm = (h - m) - logf(ssum);
  out[(size_t)n * 64 + f] = h;
  out[(size_t)NN * 64 + (size_t)n * 64 + f] = lsm;
}

// ---------------------------------------------------------------------------
extern "C" void kernel_launch(void* const* d_in, const int* in_sizes, int n_in,
                              void* d_out, int out_size, void* d_ws, size_t ws_size,
                              hipStream_t stream) {
  const float* x = (const float*)d_in[0];
  const int* ei = (const int*)d_in[1];  // [2, E] as int32
  const float* W1 = (const float*)d_in[2];
  const float* b1 = (const float*)d_in[3];
  const float* W2 = (const float*)d_in[4];
  const float* b2 = (const float*)d_in[5];
  const float* g1 = (const float*)d_in[6];
  const float* bt1 = (const float*)d_in[7];
  const float* e1 = (const float*)d_in[8];
  const float* W3 = (const float*)d_in[9];
  const float* b3 = (const float*)d_in[10];
  const float* W4 = (const float*)d_in[11];
  const float* b4 = (const float*)d_in[12];
  const float* g2 = (const float*)d_in[13];
  const float* bt2 = (const float*)d_in[14];
  const float* e2 = (const float*)d_in[15];
  const int* src = ei;
  const int* dst = ei + NE;

  char* ws = (char*)d_ws;
  // Fixed layout (slab last, sized by runtime group count):
  unsigned short* xb = (unsigned short*)(ws);              // 12.8 MB bf16 [NN][64]
  unsigned short* h2b = (unsigned short*)(ws + 12800000);  // 12.8 MB bf16 [NN][64]
  int* ed = (int*)(ws + 25600000);                         // 6.4 MB packed edges
  int* blockHist = (int*)(ws + 32000000);                  // 98*3128*4 = 1,226,176
  int* colTot = (int*)(ws + 33226176);                     // 12,512
  int* base = (int*)(ws + 33238688);                       // 12,516 (+pad)
  int* deg = (int*)(ws + 33251328);                        // 400,000
  double* st1 = (double*)(ws + 33651328);                  // 1024
  double* st2 = (double*)(ws + 33652352);                  // 1024
  float* AB1 = (float*)(ws + 33653376);                    // 256
  float* AB2 = (float*)(ws + 33653632);                    // 256
  unsigned short* Wbb = (unsigned short*)(ws + 33653888);  // 32768
  float* slab = (float*)(ws + 33689600);                   // f32 partials
  float* out = (float*)d_out;

  // Pick group count from available slab space (smaller ng = fewer launches).
  // need(ng) = 33,689,600 + ceil(391/ng)*524288 bytes.
  size_t avail = ws_size - 33689600;
  int ng = 8;
  if (avail >= (size_t)391 * 524288) ng = 1;
  else if (avail >= (size_t)196 * 524288) ng = 2;
  else if (avail >= (size_t)98 * 524288) ng = 4;
  const int gch = (NCH + ng - 1) / ng;   // chunks per group
  const int grptiles = gch * 16;         // slab tiles per range per group

  hipMemsetAsync(ws + 33251328, 0, 402048, stream);  // deg + st1 + st2

  k_cvtW<<<16, 256, 0, stream>>>(W1, W2, W3, W4, Wbb);
  k_cvtX<<<3125, 256, 0, stream>>>(x, xb);

  k_phist<<<EBK, 256, 0, stream>>>(src, dst, blockHist);
  k_colscan<<<NBK, 256, 0, stream>>>(blockHist, colTot);
  k_basescan<<<1, 1024, 0, stream>>>(colTot, base);
  k_escat<<<EBK, 256, 0, stream>>>(src, dst, blockHist, base, ed);
  k_deg<<<782, 256, 0, stream>>>(dst, deg);

  // --- Layer 1: push(xb) -> slab -> mlp -> h2b ---
  for (int g = 0, c0 = 0; g < ng && c0 < NCH; g++, c0 += gch) {
    int ch = NCH - c0 < gch ? NCH - c0 : gch;
    k_push<<<ch * 8, 256, 0, stream>>>(xb, ed, base, slab, c0 * 8, grptiles);
    int nt = NTILES - c0 * 16 < grptiles ? NTILES - c0 * 16 : grptiles;
    k_mlp<0><<<(nt + 3) / 4, 256, 0, stream>>>(slab, xb, Wbb, b1, b2, e1, nullptr,
                                               nullptr, c0 * 256, nt, grptiles,
                                               h2b, st1);
  }
  k_bnfin<<<1, 64, 0, stream>>>(st1, g1, bt1, AB1);

  // --- Layer 2: push(h2b raw) -> slab -> mlp (BN1 affine via linearity) -> xb ---
  for (int g = 0, c0 = 0; g < ng && c0 < NCH; g++, c0 += gch) {
    int ch = NCH - c0 < gch ? NCH - c0 : gch;
    k_push<<<ch * 8, 256, 0, stream>>>(h2b, ed, base, slab, c0 * 8, grptiles);
    int nt = NTILES - c0 * 16 < grptiles ? NTILES - c0 * 16 : grptiles;
    k_mlp<1><<<(nt + 3) / 4, 256, 0, stream>>>(slab, h2b, Wbb + 8192, b3, b4, e2,
                                               AB1, deg, c0 * 256, nt, grptiles,
                                               xb, st2);
  }
  k_bnfin<<<1, 64, 0, stream>>>(st2, g2, bt2, AB2);

  // --- Epilogue: BN2 + log_softmax (h2 lives in xb) ---
  k_out<<<NN / 4, 256, 0, stream>>>(xb, AB2, out);
}